// Round 4
// baseline (383.210 us; speedup 1.0000x reference)
//
#include <hip/hip_runtime.h>
#include <hip/hip_bf16.h>

#define NN 100000
#define EE 1600000
#define ETOT (EE + NN)          // 1,700,000 edges incl. self-loops
#define IND 32
#define HIDD 64
#define NHEADS 4
#define OUTD 32
#define HID2D 32
#define LOG2E 1.44269504f

#define BSH 8                   // 256 nodes per bucket
#define NBUCK 391               // ceil(NN / 256)
#define CAP 5120                // max edges per bucket (mean ~4348)
#define EPB 8192                // edges per bin block (count + rescatter)
#define L2NB 128                // nodes per k_lin2 block

typedef unsigned int uint;

__device__ __forceinline__ uint pack2(float a, float b) {
  uint lo = (uint)__bfloat16_as_ushort(__float2bfloat16(a));
  uint hi = (uint)__bfloat16_as_ushort(__float2bfloat16(b));
  return (hi << 16) | lo;
}
__device__ __forceinline__ float lo2f(uint w) { return __uint_as_float(w << 16); }
// raw reinterpret: low 16 bits act as <=1-ulp mantissa noise (saves the AND)
__device__ __forceinline__ float hi2r(uint w) { return __uint_as_float(w); }

// ---------- linear 1: h1(bf16) = x @ W1 ; as1/ad1 (pre-scaled by log2e) ----------
// block 0 also zeroes bcur (replaces a memset dispatch; k_bin runs after).
__global__ __launch_bounds__(256) void k_lin1(
    const float* __restrict__ x, const float* __restrict__ W1,
    const float* __restrict__ atsrc, const float* __restrict__ atdst,
    uint* __restrict__ h1u, float* __restrict__ as1, float* __restrict__ ad1,
    int* __restrict__ bcur) {
  __shared__ float Ws[IND * HIDD];
  __shared__ float xs[8 * IND];
  __shared__ float atS[HIDD], atD[HIDD];
  int t = threadIdx.x;
  if (blockIdx.x == 0) { bcur[t] = 0; bcur[t + 256] = 0; }
  for (int i = t; i < IND * HIDD; i += 256) Ws[i] = W1[i];
  if (t < HIDD) { atS[t] = atsrc[t]; atD[t] = atdst[t]; }
  xs[t] = x[blockIdx.x * 256 + t];
  __syncthreads();
  int nl = t >> 5, tl = t & 31;
  int node = blockIdx.x * 8 + nl;
  int j0 = 2 * tl, j1 = j0 + 1;
  float a0 = 0.f, a1 = 0.f;
#pragma unroll
  for (int k = 0; k < IND; k++) {
    float xv = xs[nl * IND + k];
    a0 += xv * Ws[k * HIDD + j0];
    a1 += xv * Ws[k * HIDD + j1];
  }
  h1u[node * 32 + tl] = pack2(a0, a1);
  float ps = a0 * atS[j0] + a1 * atS[j1];
  float pd = a0 * atD[j0] + a1 * atD[j1];
#pragma unroll
  for (int off = 4; off >= 1; off >>= 1) {
    ps += __shfl_down(ps, off, 8);
    pd += __shfl_down(pd, off, 8);
  }
  if ((tl & 7) == 0) {
    as1[node * NHEADS + (tl >> 3)] = ps * LOG2E;
    ad1[node * NHEADS + (tl >> 3)] = pd * LOG2E;
  }
}

// ---------- pass 1: bucket edges by dst>>8 (count, reserve, re-read & scatter) ----------
__global__ __launch_bounds__(256) void k_bin(const int* __restrict__ ei,
                                             int* __restrict__ bcur,
                                             int* __restrict__ bins) {
  __shared__ int cnt[NBUCK];
  int t = threadIdx.x;
  for (int i = t; i < NBUCK; i += 256) cnt[i] = 0;
  __syncthreads();
  int base = blockIdx.x * EPB;
  int lim = base + EPB; if (lim > ETOT) lim = ETOT;
  for (int i = base + t; i < lim; i += 256) {
    int d = (i < EE) ? ei[EE + i] : (i - EE);
    atomicAdd(&cnt[d >> BSH], 1);
  }
  __syncthreads();
  for (int i = t; i < NBUCK; i += 256) cnt[i] = atomicAdd(&bcur[i], cnt[i]);
  __syncthreads();
  for (int i = base + t; i < lim; i += 256) {
    int s, d;
    if (i < EE) { s = ei[i]; d = ei[EE + i]; } else { s = i - EE; d = s; }
    int bk = d >> BSH;
    int pos = atomicAdd(&cnt[bk], 1);
    bins[bk * CAP + pos] = (s << BSH) | (d & ((1 << BSH) - 1));
  }
}

// ---------- pass 2: per-bucket local CSR (391 blocks), inline 512-scan ----------
// srcs entries are stored PRE-SCALED by 8 (uint4/uint2 row offsets).
__global__ __launch_bounds__(256) void k_csr(const int* __restrict__ bcur,
                                             const int* __restrict__ bins,
                                             int* __restrict__ rowp,
                                             int* __restrict__ srcs) {
  __shared__ int lrec[CAP];          // 20KB
  __shared__ int sA[512], sB[512];
  __shared__ int ldeg[256];
  int b = blockIdx.x, t = threadIdx.x;
  if (b == 0 && t == 0) rowp[NN] = ETOT;
  sA[t] = (t < NBUCK) ? bcur[t] : 0;
  sA[t + 256] = (t + 256 < NBUCK) ? bcur[t + 256] : 0;
  __syncthreads();
  int* in = sA; int* out = sB;
  for (int off = 1; off < 512; off <<= 1) {
    for (int i = t; i < 512; i += 256)
      out[i] = in[i] + ((i >= off) ? in[i - off] : 0);
    __syncthreads();
    int* tmp = in; in = out; out = tmp;
  }
  int gb = (b == 0) ? 0 : in[b - 1];
  __syncthreads();
  int count = bcur[b]; if (count > CAP) count = CAP;
  ldeg[t] = 0;
  __syncthreads();
  for (int i = t; i < count; i += 256) {
    int r = bins[b * CAP + i];
    lrec[i] = r;
    atomicAdd(&ldeg[r & 255], 1);
  }
  __syncthreads();
  int dv = ldeg[t];
  sA[t] = dv;
  __syncthreads();
  in = sA; out = sB;
  for (int off = 1; off < 256; off <<= 1) {
    out[t] = in[t] + ((t >= off) ? in[t - off] : 0);
    __syncthreads();
    int* tmp = in; in = out; out = tmp;
  }
  int nb = b << BSH;
  int ex = in[t] - dv;               // exclusive scan
  if (nb + t < NN) rowp[nb + t] = gb + ex;
  ldeg[t] = ex;                      // reuse as scatter cursor
  __syncthreads();
  for (int i = t; i < count; i += 256) {
    int r = lrec[i];
    int pos = atomicAdd(&ldeg[r & 255], 1);
    srcs[gb + pos] = (r >> BSH) << 3;   // pre-scaled src*8
  }
}

// ---------- GAT1 aggregation + bias + BN1 + ReLU, QUAD-node waves ----------
// 4 independent gather pipelines per wave; clamped depth-2 prefetch.
__global__ __launch_bounds__(256, 4) void k_agg1(
    const int* __restrict__ rowp, const int* __restrict__ srcs,
    const uint* __restrict__ h1u, const float* __restrict__ as1,
    const float* __restrict__ ad1, const float* __restrict__ b1,
    const float* __restrict__ g, const float* __restrict__ bb,
    const float* __restrict__ m, const float* __restrict__ v,
    float* __restrict__ hbn) {
  int t = threadIdx.x;
  int wid = t >> 6, lane = t & 63;
  int n0 = blockIdx.x * 16 + wid * 4;
  int slot = lane >> 3;
  int fl = lane & 7;
  int hd = fl >> 1;
  int rp[5];
#pragma unroll
  for (int k = 0; k < 5; k++) rp[k] = rowp[n0 + k];
  const uint4* h14 = (const uint4*)h1u;
  float acc[4][8], l[4], adv[4], as[4];
  int p[4], p1[4], lp[4], en[4], s1v[4];
  uint4 w[4];
#pragma unroll
  for (int k = 0; k < 4; k++) {
    adv[k] = ad1[(n0 + k) * NHEADS + hd];
    en[k] = rp[k + 1];
    lp[k] = en[k] - 1;                 // deg >= 1 (self-loop)
    p[k] = rp[k] + slot;
    int pc = p[k] < lp[k] ? p[k] : lp[k];
    int s0 = srcs[pc];                 // pre-scaled s*8
    w[k] = h14[s0 + fl];
    as[k] = as1[(s0 >> 1) + hd];
    p1[k] = p[k] + 8;
    int pc1 = p1[k] < lp[k] ? p1[k] : lp[k];
    s1v[k] = srcs[pc1];
    l[k] = 0.f;
#pragma unroll
    for (int i = 0; i < 8; i++) acc[k][i] = 0.f;
  }
  while (p[0] < en[0] || p[1] < en[1] || p[2] < en[2] || p[3] < en[3]) {
    uint4 wn[4]; float an[4]; int s2[4];
#pragma unroll
    for (int k = 0; k < 4; k++) {
      wn[k] = h14[s1v[k] + fl];
      an[k] = as1[(s1v[k] >> 1) + hd];
      int p2 = p1[k] + 8;
      int pc = p2 < lp[k] ? p2 : lp[k];
      s2[k] = srcs[pc];
    }
#pragma unroll
    for (int k = 0; k < 4; k++) {
      if (p[k] < en[k]) {
        float e = as[k] + adv[k];
        e = fmaxf(e, 0.2f * e);
        float ex = exp2f(e);           // as/ad pre-scaled by log2e
        l[k] += ex;
        acc[k][0] += ex * lo2f(w[k].x); acc[k][1] += ex * hi2r(w[k].x);
        acc[k][2] += ex * lo2f(w[k].y); acc[k][3] += ex * hi2r(w[k].y);
        acc[k][4] += ex * lo2f(w[k].z); acc[k][5] += ex * hi2r(w[k].z);
        acc[k][6] += ex * lo2f(w[k].w); acc[k][7] += ex * hi2r(w[k].w);
      }
      w[k] = wn[k]; as[k] = an[k]; s1v[k] = s2[k];
      p[k] = p1[k]; p1[k] += 8;
    }
  }
#pragma unroll
  for (int off = 8; off <= 32; off <<= 1) {
#pragma unroll
    for (int k = 0; k < 4; k++) {
#pragma unroll
      for (int i = 0; i < 8; i++) acc[k][i] += __shfl_xor(acc[k][i], off, 64);
      l[k] += __shfl_xor(l[k], off, 64);
    }
  }
  if (slot < 4) {
    float lsum = 0.f, av[8];
#pragma unroll
    for (int i = 0; i < 8; i++) av[i] = 0.f;
#pragma unroll
    for (int k = 0; k < 4; k++) {
      if (slot == k) {
        lsum = l[k];
#pragma unroll
        for (int i = 0; i < 8; i++) av[i] = acc[k][i];
      }
    }
    int node = n0 + slot;
    float li = 1.f / (lsum + 1e-16f);
    int fb = fl * 8;
    float o[8];
#pragma unroll
    for (int i = 0; i < 8; i++) {
      int j = fb + i;
      float ov = av[i] * li + b1[j];
      ov = (ov - m[j]) * rsqrtf(v[j] + 1e-5f) * g[j] + bb[j];
      o[i] = fmaxf(ov, 0.f);
    }
    float4* dst = (float4*)(hbn + node * HIDD + fb);
    dst[0] = make_float4(o[0], o[1], o[2], o[3]);
    dst[1] = make_float4(o[4], o[5], o[6], o[7]);
  }
}

// ---------- linear 2, DS-minimal: h2(bf16) = hbn @ W2 ; as2/ad2 ----------
// 32 nodes per wave (8 j-lane groups x 4 nodes). Per k-step: one b128 W read
// (broadcast across groups, conflict-free) + one b128 read of the transposed,
// XOR-swizzled x tile (8 distinct 4-word slots -> all 32 banks) feeds 16 FMA.
// 128 DS ops per wave for 32 nodes (vs ~192 per 4 nodes before).
__global__ __launch_bounds__(256) void k_lin2(
    const float* __restrict__ hbn, const float* __restrict__ W2,
    const float* __restrict__ atsrc, const float* __restrict__ atdst,
    uint* __restrict__ h2u, float* __restrict__ as2, float* __restrict__ ad2) {
  __shared__ float xsT[HIDD][L2NB];   // 32KB, transposed + swizzled node slots
  __shared__ float Wp[HIDD * OUTD];   // 8KB, [k][j] as in global
  __shared__ float atS[OUTD], atD[OUTD];
  int t = threadIdx.x;
  int nb = blockIdx.x * L2NB;
  for (int i = t; i < HIDD * OUTD; i += 256) Wp[i] = W2[i];
  if (t < OUTD) { atS[t] = atsrc[t]; atD[t] = atdst[t]; }
  // stage + transpose: 128 nodes x 16 float4, coalesced reads,
  // swizzled writes (lanes sharing a node differ in c -> 8 banks, 2-way free)
#pragma unroll
  for (int i = 0; i < 8; i++) {
    int idx = t + i * 256;
    int node = idx >> 4, c = idx & 15;
    int gnode = nb + node;
    float4 vv = make_float4(0.f, 0.f, 0.f, 0.f);
    if (gnode < NN) vv = ((const float4*)hbn)[gnode * 16 + c];
    int ns = node ^ ((c & 7) << 2);
    xsT[4 * c + 0][ns] = vv.x;
    xsT[4 * c + 1][ns] = vv.y;
    xsT[4 * c + 2][ns] = vv.z;
    xsT[4 * c + 3][ns] = vv.w;
  }
  __syncthreads();
  int w = t >> 6, lane = t & 63;
  int gq = lane >> 3, tl = lane & 7;
  int base = w * 32 + gq * 4;          // logical first node of this lane's quad
  int j0 = tl * 4;                     // 4 output columns per lane
  float acc[4][4];
#pragma unroll
  for (int e = 0; e < 4; e++)
#pragma unroll
    for (int d = 0; d < 4; d++) acc[e][d] = 0.f;
#pragma unroll
  for (int k = 0; k < HIDD; k++) {
    float4 wv = *(const float4*)&Wp[k * OUTD + j0];
    int swz = ((k >> 2) & 7) << 2;
    float4 xv = *(const float4*)&xsT[k][base ^ swz];
    acc[0][0] += xv.x * wv.x; acc[0][1] += xv.x * wv.y;
    acc[0][2] += xv.x * wv.z; acc[0][3] += xv.x * wv.w;
    acc[1][0] += xv.y * wv.x; acc[1][1] += xv.y * wv.y;
    acc[1][2] += xv.y * wv.z; acc[1][3] += xv.y * wv.w;
    acc[2][0] += xv.z * wv.x; acc[2][1] += xv.z * wv.y;
    acc[2][2] += xv.z * wv.z; acc[2][3] += xv.z * wv.w;
    acc[3][0] += xv.w * wv.x; acc[3][1] += xv.w * wv.y;
    acc[3][2] += xv.w * wv.z; acc[3][3] += xv.w * wv.w;
  }
#pragma unroll
  for (int e = 0; e < 4; e++) {
    int node = nb + base + e;
    float ps = acc[e][0] * atS[j0] + acc[e][1] * atS[j0 + 1] +
               acc[e][2] * atS[j0 + 2] + acc[e][3] * atS[j0 + 3];
    float pd = acc[e][0] * atD[j0] + acc[e][1] * atD[j0 + 1] +
               acc[e][2] * atD[j0 + 2] + acc[e][3] * atD[j0 + 3];
#pragma unroll
    for (int off = 1; off <= 4; off <<= 1) {
      ps += __shfl_xor(ps, off, 64);
      pd += __shfl_xor(pd, off, 64);
    }
    if (node < NN) {
      uint2 pk;
      pk.x = pack2(acc[e][0], acc[e][1]);
      pk.y = pack2(acc[e][2], acc[e][3]);
      ((uint2*)h2u)[node * 8 + tl] = pk;
      if (tl == 0) { as2[node] = ps * LOG2E; ad2[node] = pd * LOG2E; }
    }
  }
}

// ---------- GAT2 aggregation + bias + BN2 + ReLU, QUAD-node waves ----------
__global__ __launch_bounds__(256, 4) void k_agg2(
    const int* __restrict__ rowp, const int* __restrict__ srcs,
    const uint* __restrict__ h2u, const float* __restrict__ as2,
    const float* __restrict__ ad2, const float* __restrict__ b2v,
    const float* __restrict__ g, const float* __restrict__ bb,
    const float* __restrict__ m, const float* __restrict__ v,
    float* __restrict__ out_emb) {
  int t = threadIdx.x;
  int wid = t >> 6, lane = t & 63;
  int n0 = blockIdx.x * 16 + wid * 4;
  int slot = lane >> 3;
  int fl = lane & 7;                   // feats fl*4..fl*4+3
  int rp[5];
#pragma unroll
  for (int k = 0; k < 5; k++) rp[k] = rowp[n0 + k];
  const uint2* h22 = (const uint2*)h2u;
  float acc[4][4], l[4], adv[4], as[4];
  int p[4], p1[4], lp[4], en[4], s1v[4];
  uint2 w[4];
#pragma unroll
  for (int k = 0; k < 4; k++) {
    adv[k] = ad2[n0 + k];
    en[k] = rp[k + 1];
    lp[k] = en[k] - 1;
    p[k] = rp[k] + slot;
    int pc = p[k] < lp[k] ? p[k] : lp[k];
    int s0 = srcs[pc];                 // pre-scaled s*8 (= uint2 row offset)
    w[k] = h22[s0 + fl];
    as[k] = as2[s0 >> 3];
    p1[k] = p[k] + 8;
    int pc1 = p1[k] < lp[k] ? p1[k] : lp[k];
    s1v[k] = srcs[pc1];
    l[k] = 0.f;
#pragma unroll
    for (int i = 0; i < 4; i++) acc[k][i] = 0.f;
  }
  while (p[0] < en[0] || p[1] < en[1] || p[2] < en[2] || p[3] < en[3]) {
    uint2 wn[4]; float an[4]; int s2[4];
#pragma unroll
    for (int k = 0; k < 4; k++) {
      wn[k] = h22[s1v[k] + fl];
      an[k] = as2[s1v[k] >> 3];
      int p2 = p1[k] + 8;
      int pc = p2 < lp[k] ? p2 : lp[k];
      s2[k] = srcs[pc];
    }
#pragma unroll
    for (int k = 0; k < 4; k++) {
      if (p[k] < en[k]) {
        float e = as[k] + adv[k];
        e = fmaxf(e, 0.2f * e);
        float ex = exp2f(e);
        l[k] += ex;
        acc[k][0] += ex * lo2f(w[k].x); acc[k][1] += ex * hi2r(w[k].x);
        acc[k][2] += ex * lo2f(w[k].y); acc[k][3] += ex * hi2r(w[k].y);
      }
      w[k] = wn[k]; as[k] = an[k]; s1v[k] = s2[k];
      p[k] = p1[k]; p1[k] += 8;
    }
  }
#pragma unroll
  for (int off = 8; off <= 32; off <<= 1) {
#pragma unroll
    for (int k = 0; k < 4; k++) {
#pragma unroll
      for (int i = 0; i < 4; i++) acc[k][i] += __shfl_xor(acc[k][i], off, 64);
      l[k] += __shfl_xor(l[k], off, 64);
    }
  }
  if (slot < 4) {
    float lsum = 0.f, av[4];
#pragma unroll
    for (int i = 0; i < 4; i++) av[i] = 0.f;
#pragma unroll
    for (int k = 0; k < 4; k++) {
      if (slot == k) {
        lsum = l[k];
#pragma unroll
        for (int i = 0; i < 4; i++) av[i] = acc[k][i];
      }
    }
    int node = n0 + slot;
    float li = 1.f / (lsum + 1e-16f);
    int fb = fl * 4;
    float o[4];
#pragma unroll
    for (int i = 0; i < 4; i++) {
      int j = fb + i;
      float ov = av[i] * li + b2v[j];
      ov = (ov - m[j]) * rsqrtf(v[j] + 1e-5f) * g[j] + bb[j];
      o[i] = fmaxf(ov, 0.f);
    }
    *(float4*)(out_emb + node * OUTD + fb) = make_float4(o[0], o[1], o[2], o[3]);
  }
}

// ---------- classifier + regressor heads (thread per node) ----------
__global__ __launch_bounds__(256) void k_mlp(
    const float* __restrict__ embf,
    const float* __restrict__ cw1, const float* __restrict__ cb1,
    const float* __restrict__ cw2, const float* __restrict__ cb2,
    const float* __restrict__ rw1, const float* __restrict__ rb1,
    const float* __restrict__ rw2, const float* __restrict__ rb2,
    float* __restrict__ out_roles, float* __restrict__ out_energy) {
  __shared__ float C1[OUTD * HID2D], R1[OUTD * HID2D];
  __shared__ float C2[HID2D * 3], CB1[HID2D], RB1[HID2D], R2[HID2D];
  __shared__ float CB2v[3], RB2v;
  int t = threadIdx.x;
  for (int i = t; i < OUTD * HID2D; i += 256) { C1[i] = cw1[i]; R1[i] = rw1[i]; }
  if (t < HID2D) { CB1[t] = cb1[t]; RB1[t] = rb1[t]; R2[t] = rw2[t]; }
  if (t < HID2D * 3) C2[t] = cw2[t];
  if (t < 3) CB2v[t] = cb2[t];
  if (t == 0) RB2v = rb2[0];
  __syncthreads();
  int node = blockIdx.x * 256 + t;
  if (node >= NN) return;
  float e[OUTD];
#pragma unroll
  for (int k = 0; k < OUTD; k++) e[k] = embf[node * OUTD + k];
  float r0 = CB2v[0], r1 = CB2v[1], r2 = CB2v[2], en = RB2v;
  for (int j = 0; j < HID2D; j++) {
    float hc = CB1[j], hr = RB1[j];
#pragma unroll
    for (int k = 0; k < OUTD; k++) {
      hc += e[k] * C1[k * HID2D + j];
      hr += e[k] * R1[k * HID2D + j];
    }
    hc = fmaxf(hc, 0.f);
    hr = fmaxf(hr, 0.f);
    r0 += hc * C2[j * 3 + 0];
    r1 += hc * C2[j * 3 + 1];
    r2 += hc * C2[j * 3 + 2];
    en += hr * R2[j];
  }
  out_roles[node * 3 + 0] = r0;
  out_roles[node * 3 + 1] = r1;
  out_roles[node * 3 + 2] = r2;
  out_energy[node] = en;
}

extern "C" void kernel_launch(void* const* d_in, const int* in_sizes, int n_in,
                              void* d_out, int out_size, void* d_ws, size_t ws_size,
                              hipStream_t stream) {
  const float* x    = (const float*)d_in[0];
  const int*   ei   = (const int*)d_in[1];
  const float* W1   = (const float*)d_in[2];
  const float* as1w = (const float*)d_in[3];
  const float* ad1w = (const float*)d_in[4];
  const float* b1   = (const float*)d_in[5];
  const float* W2   = (const float*)d_in[6];
  const float* as2w = (const float*)d_in[7];
  const float* ad2w = (const float*)d_in[8];
  const float* b2v  = (const float*)d_in[9];
  const float* bn1g = (const float*)d_in[10];
  const float* bn1b = (const float*)d_in[11];
  const float* bn1m = (const float*)d_in[12];
  const float* bn1v = (const float*)d_in[13];
  const float* bn2g = (const float*)d_in[14];
  const float* bn2b = (const float*)d_in[15];
  const float* bn2m = (const float*)d_in[16];
  const float* bn2v = (const float*)d_in[17];
  const float* cw1  = (const float*)d_in[18];
  const float* cb1  = (const float*)d_in[19];
  const float* cw2  = (const float*)d_in[20];
  const float* cb2  = (const float*)d_in[21];
  const float* rw1  = (const float*)d_in[22];
  const float* rb1  = (const float*)d_in[23];
  const float* rw2  = (const float*)d_in[24];
  const float* rb2  = (const float*)d_in[25];

  // workspace (~56 MB), no aliasing except h2u reusing dead h1u
  uint*  h1u = (uint*)d_ws;               // N*32 uints (bf16x2) = 12.8MB
  float* hbn = (float*)(h1u + NN * 32);   // N*64 f32 = 25.6MB
  float* as1 = hbn + NN * HIDD;           // N*4
  float* ad1 = as1 + NN * NHEADS;         // N*4
  int* rowp  = (int*)(ad1 + NN * NHEADS); // N+1
  int* srcs  = rowp + NN + 1;             // ETOT
  int* bcur  = srcs + ETOT;               // 512
  int* bins  = bcur + 512;                // NBUCK*CAP = 2.0M ints (8MB)
  uint* h2u  = h1u;                       // N*16 uints fits h1u slot (h1 dead)
  float* as2 = as1;
  float* ad2 = ad1;

  float* out        = (float*)d_out;
  float* out_emb    = out;                   // N*32
  float* out_roles  = out + NN * OUTD;       // N*3
  float* out_energy = out + NN * (OUTD + 3); // N*1

  k_lin1<<<NN / 8, 256, 0, stream>>>(x, W1, as1w, ad1w, h1u, as1, ad1, bcur);
  k_bin<<<(ETOT + EPB - 1) / EPB, 256, 0, stream>>>(ei, bcur, bins);
  k_csr<<<NBUCK, 256, 0, stream>>>(bcur, bins, rowp, srcs);
  k_agg1<<<NN / 16, 256, 0, stream>>>(rowp, srcs, h1u, as1, ad1, b1, bn1g, bn1b, bn1m, bn1v, hbn);
  k_lin2<<<(NN + L2NB - 1) / L2NB, 256, 0, stream>>>(hbn, W2, as2w, ad2w, h2u, as2, ad2);
  k_agg2<<<NN / 16, 256, 0, stream>>>(rowp, srcs, h2u, as2, ad2, b2v, bn2g, bn2b, bn2m, bn2v, out_emb);
  k_mlp<<<(NN + 255) / 256, 256, 0, stream>>>(out_emb, cw1, cb1, cw2, cb2, rw1, rb1, rw2, rb2, out_roles, out_energy);
}

// Round 5
// 309.148 us; speedup vs baseline: 1.2396x; 1.2396x over previous
//
#include <hip/hip_runtime.h>
#include <hip/hip_bf16.h>

#define NN 100000
#define EE 1600000
#define ETOT (EE + NN)          // 1,700,000 edges incl. self-loops
#define IND 32
#define HIDD 64
#define NHEADS 4
#define OUTD 32
#define HID2D 32
#define LOG2E 1.44269504f

#define BSH 8                   // 256 nodes per bucket
#define NBUCK 391               // ceil(NN / 256)
#define CAP 5120                // max edges per bucket (mean ~4348)
#define EPB 8192                // edges per bin block (count + rescatter)
#define L2NB 128                // nodes per k_lin2 block

typedef unsigned int uint;

__device__ __forceinline__ uint pack2(float a, float b) {
  uint lo = (uint)__bfloat16_as_ushort(__float2bfloat16(a));
  uint hi = (uint)__bfloat16_as_ushort(__float2bfloat16(b));
  return (hi << 16) | lo;
}
__device__ __forceinline__ float lo2f(uint w) { return __uint_as_float(w << 16); }
// raw reinterpret: low 16 bits act as <=1-ulp mantissa noise (saves the AND)
__device__ __forceinline__ float hi2r(uint w) { return __uint_as_float(w); }

// ---------- linear 1: h1(bf16) = x @ W1 ; as1/ad1 (pre-scaled by log2e) ----------
// block 0 also zeroes bcur (replaces a memset dispatch; k_bin runs after).
__global__ __launch_bounds__(256) void k_lin1(
    const float* __restrict__ x, const float* __restrict__ W1,
    const float* __restrict__ atsrc, const float* __restrict__ atdst,
    uint* __restrict__ h1u, float* __restrict__ as1, float* __restrict__ ad1,
    int* __restrict__ bcur) {
  __shared__ float Ws[IND * HIDD];
  __shared__ float xs[8 * IND];
  __shared__ float atS[HIDD], atD[HIDD];
  int t = threadIdx.x;
  if (blockIdx.x == 0) { bcur[t] = 0; bcur[t + 256] = 0; }
  for (int i = t; i < IND * HIDD; i += 256) Ws[i] = W1[i];
  if (t < HIDD) { atS[t] = atsrc[t]; atD[t] = atdst[t]; }
  xs[t] = x[blockIdx.x * 256 + t];
  __syncthreads();
  int nl = t >> 5, tl = t & 31;
  int node = blockIdx.x * 8 + nl;
  int j0 = 2 * tl, j1 = j0 + 1;
  float a0 = 0.f, a1 = 0.f;
#pragma unroll
  for (int k = 0; k < IND; k++) {
    float xv = xs[nl * IND + k];
    a0 += xv * Ws[k * HIDD + j0];
    a1 += xv * Ws[k * HIDD + j1];
  }
  h1u[node * 32 + tl] = pack2(a0, a1);
  float ps = a0 * atS[j0] + a1 * atS[j1];
  float pd = a0 * atD[j0] + a1 * atD[j1];
#pragma unroll
  for (int off = 4; off >= 1; off >>= 1) {
    ps += __shfl_down(ps, off, 8);
    pd += __shfl_down(pd, off, 8);
  }
  if ((tl & 7) == 0) {
    as1[node * NHEADS + (tl >> 3)] = ps * LOG2E;
    ad1[node * NHEADS + (tl >> 3)] = pd * LOG2E;
  }
}

// ---------- pass 1: bucket edges by dst>>8 (count, reserve, re-read & scatter) ----------
__global__ __launch_bounds__(256) void k_bin(const int* __restrict__ ei,
                                             int* __restrict__ bcur,
                                             int* __restrict__ bins) {
  __shared__ int cnt[NBUCK];
  int t = threadIdx.x;
  for (int i = t; i < NBUCK; i += 256) cnt[i] = 0;
  __syncthreads();
  int base = blockIdx.x * EPB;
  int lim = base + EPB; if (lim > ETOT) lim = ETOT;
  for (int i = base + t; i < lim; i += 256) {
    int d = (i < EE) ? ei[EE + i] : (i - EE);
    atomicAdd(&cnt[d >> BSH], 1);
  }
  __syncthreads();
  for (int i = t; i < NBUCK; i += 256) cnt[i] = atomicAdd(&bcur[i], cnt[i]);
  __syncthreads();
  for (int i = base + t; i < lim; i += 256) {
    int s, d;
    if (i < EE) { s = ei[i]; d = ei[EE + i]; } else { s = i - EE; d = s; }
    int bk = d >> BSH;
    int pos = atomicAdd(&cnt[bk], 1);
    bins[bk * CAP + pos] = (s << BSH) | (d & ((1 << BSH) - 1));
  }
}

// ---------- pass 2: per-bucket local CSR (391 blocks), inline 512-scan ----------
// srcs entries are stored PRE-SCALED by 8 (uint4/uint2 row offsets).
__global__ __launch_bounds__(256) void k_csr(const int* __restrict__ bcur,
                                             const int* __restrict__ bins,
                                             int* __restrict__ rowp,
                                             int* __restrict__ srcs) {
  __shared__ int lrec[CAP];          // 20KB
  __shared__ int sA[512], sB[512];
  __shared__ int ldeg[256];
  int b = blockIdx.x, t = threadIdx.x;
  if (b == 0 && t == 0) rowp[NN] = ETOT;
  sA[t] = (t < NBUCK) ? bcur[t] : 0;
  sA[t + 256] = (t + 256 < NBUCK) ? bcur[t + 256] : 0;
  __syncthreads();
  int* in = sA; int* out = sB;
  for (int off = 1; off < 512; off <<= 1) {
    for (int i = t; i < 512; i += 256)
      out[i] = in[i] + ((i >= off) ? in[i - off] : 0);
    __syncthreads();
    int* tmp = in; in = out; out = tmp;
  }
  int gb = (b == 0) ? 0 : in[b - 1];
  __syncthreads();
  int count = bcur[b]; if (count > CAP) count = CAP;
  ldeg[t] = 0;
  __syncthreads();
  for (int i = t; i < count; i += 256) {
    int r = bins[b * CAP + i];
    lrec[i] = r;
    atomicAdd(&ldeg[r & 255], 1);
  }
  __syncthreads();
  int dv = ldeg[t];
  sA[t] = dv;
  __syncthreads();
  in = sA; out = sB;
  for (int off = 1; off < 256; off <<= 1) {
    out[t] = in[t] + ((t >= off) ? in[t - off] : 0);
    __syncthreads();
    int* tmp = in; in = out; out = tmp;
  }
  int nb = b << BSH;
  int ex = in[t] - dv;               // exclusive scan
  if (nb + t < NN) rowp[nb + t] = gb + ex;
  ldeg[t] = ex;                      // reuse as scatter cursor
  __syncthreads();
  for (int i = t; i < count; i += 256) {
    int r = lrec[i];
    int pos = atomicAdd(&ldeg[r & 255], 1);
    srcs[gb + pos] = (r >> BSH) << 3;   // pre-scaled src*8
  }
}

// ---------- GAT1 aggregation + bias + BN1 + ReLU, QUAD-node waves ----------
// 4 independent gather pipelines per wave; clamped depth-2 prefetch.
__global__ __launch_bounds__(256, 4) void k_agg1(
    const int* __restrict__ rowp, const int* __restrict__ srcs,
    const uint* __restrict__ h1u, const float* __restrict__ as1,
    const float* __restrict__ ad1, const float* __restrict__ b1,
    const float* __restrict__ g, const float* __restrict__ bb,
    const float* __restrict__ m, const float* __restrict__ v,
    float* __restrict__ hbn) {
  int t = threadIdx.x;
  int wid = t >> 6, lane = t & 63;
  int n0 = blockIdx.x * 16 + wid * 4;
  int slot = lane >> 3;
  int fl = lane & 7;
  int hd = fl >> 1;
  int rp[5];
#pragma unroll
  for (int k = 0; k < 5; k++) rp[k] = rowp[n0 + k];
  const uint4* h14 = (const uint4*)h1u;
  float acc[4][8], l[4], adv[4], as[4];
  int p[4], p1[4], lp[4], en[4], s1v[4];
  uint4 w[4];
#pragma unroll
  for (int k = 0; k < 4; k++) {
    adv[k] = ad1[(n0 + k) * NHEADS + hd];
    en[k] = rp[k + 1];
    lp[k] = en[k] - 1;                 // deg >= 1 (self-loop)
    p[k] = rp[k] + slot;
    int pc = p[k] < lp[k] ? p[k] : lp[k];
    int s0 = srcs[pc];                 // pre-scaled s*8
    w[k] = h14[s0 + fl];
    as[k] = as1[(s0 >> 1) + hd];
    p1[k] = p[k] + 8;
    int pc1 = p1[k] < lp[k] ? p1[k] : lp[k];
    s1v[k] = srcs[pc1];
    l[k] = 0.f;
#pragma unroll
    for (int i = 0; i < 8; i++) acc[k][i] = 0.f;
  }
  while (p[0] < en[0] || p[1] < en[1] || p[2] < en[2] || p[3] < en[3]) {
    uint4 wn[4]; float an[4]; int s2[4];
#pragma unroll
    for (int k = 0; k < 4; k++) {
      wn[k] = h14[s1v[k] + fl];
      an[k] = as1[(s1v[k] >> 1) + hd];
      int p2 = p1[k] + 8;
      int pc = p2 < lp[k] ? p2 : lp[k];
      s2[k] = srcs[pc];
    }
#pragma unroll
    for (int k = 0; k < 4; k++) {
      if (p[k] < en[k]) {
        float e = as[k] + adv[k];
        e = fmaxf(e, 0.2f * e);
        float ex = exp2f(e);           // as/ad pre-scaled by log2e
        l[k] += ex;
        acc[k][0] += ex * lo2f(w[k].x); acc[k][1] += ex * hi2r(w[k].x);
        acc[k][2] += ex * lo2f(w[k].y); acc[k][3] += ex * hi2r(w[k].y);
        acc[k][4] += ex * lo2f(w[k].z); acc[k][5] += ex * hi2r(w[k].z);
        acc[k][6] += ex * lo2f(w[k].w); acc[k][7] += ex * hi2r(w[k].w);
      }
      w[k] = wn[k]; as[k] = an[k]; s1v[k] = s2[k];
      p[k] = p1[k]; p1[k] += 8;
    }
  }
#pragma unroll
  for (int off = 8; off <= 32; off <<= 1) {
#pragma unroll
    for (int k = 0; k < 4; k++) {
#pragma unroll
      for (int i = 0; i < 8; i++) acc[k][i] += __shfl_xor(acc[k][i], off, 64);
      l[k] += __shfl_xor(l[k], off, 64);
    }
  }
  if (slot < 4) {
    float lsum = 0.f, av[8];
#pragma unroll
    for (int i = 0; i < 8; i++) av[i] = 0.f;
#pragma unroll
    for (int k = 0; k < 4; k++) {
      if (slot == k) {
        lsum = l[k];
#pragma unroll
        for (int i = 0; i < 8; i++) av[i] = acc[k][i];
      }
    }
    int node = n0 + slot;
    float li = 1.f / (lsum + 1e-16f);
    int fb = fl * 8;
    float o[8];
#pragma unroll
    for (int i = 0; i < 8; i++) {
      int j = fb + i;
      float ov = av[i] * li + b1[j];
      ov = (ov - m[j]) * rsqrtf(v[j] + 1e-5f) * g[j] + bb[j];
      o[i] = fmaxf(ov, 0.f);
    }
    float4* dst = (float4*)(hbn + node * HIDD + fb);
    dst[0] = make_float4(o[0], o[1], o[2], o[3]);
    dst[1] = make_float4(o[4], o[5], o[6], o[7]);
  }
}

// ---------- linear 2, DS-minimal: h2(bf16) = hbn @ W2 ; as2/ad2 ----------
// 32 nodes per wave (8 j-lane groups x 4 nodes). Per k-step: one b128 W read
// (broadcast across groups, conflict-free) + one b128 read of the transposed,
// XOR-swizzled x tile (8 distinct 16B slots -> all 32 banks) feeds 16 FMA.
// k-loop unroll CAPPED at 4: full unroll let the scheduler hoist ~128
// ds_read_b128 -> VGPR 256 -> scratch spill (round-4: 98us, 102MB writes).
__global__ __launch_bounds__(256) void k_lin2(
    const float* __restrict__ hbn, const float* __restrict__ W2,
    const float* __restrict__ atsrc, const float* __restrict__ atdst,
    uint* __restrict__ h2u, float* __restrict__ as2, float* __restrict__ ad2) {
  __shared__ float xsT[HIDD][L2NB];   // 32KB, transposed + swizzled node slots
  __shared__ float Wp[HIDD * OUTD];   // 8KB, [k][j] as in global
  __shared__ float atS[OUTD], atD[OUTD];
  int t = threadIdx.x;
  int nb = blockIdx.x * L2NB;
  for (int i = t; i < HIDD * OUTD; i += 256) Wp[i] = W2[i];
  if (t < OUTD) { atS[t] = atsrc[t]; atD[t] = atdst[t]; }
  // stage + transpose: 128 nodes x 16 float4, coalesced reads,
  // swizzled writes (2-way bank aliasing = free)
#pragma unroll
  for (int i = 0; i < 8; i++) {
    int idx = t + i * 256;
    int node = idx >> 4, c = idx & 15;
    int gnode = nb + node;
    float4 vv = make_float4(0.f, 0.f, 0.f, 0.f);
    if (gnode < NN) vv = ((const float4*)hbn)[gnode * 16 + c];
    int ns = node ^ ((c & 7) << 2);
    xsT[4 * c + 0][ns] = vv.x;
    xsT[4 * c + 1][ns] = vv.y;
    xsT[4 * c + 2][ns] = vv.z;
    xsT[4 * c + 3][ns] = vv.w;
  }
  __syncthreads();
  int w = t >> 6, lane = t & 63;
  int gq = lane >> 3, tl = lane & 7;
  int base = w * 32 + gq * 4;          // logical first node of this lane's quad
  int j0 = tl * 4;                     // 4 output columns per lane
  float acc[4][4];
#pragma unroll
  for (int e = 0; e < 4; e++)
#pragma unroll
    for (int d = 0; d < 4; d++) acc[e][d] = 0.f;
#pragma unroll 4
  for (int k = 0; k < HIDD; k++) {
    float4 wv = *(const float4*)&Wp[k * OUTD + j0];
    int swz = ((k >> 2) & 7) << 2;
    float4 xv = *(const float4*)&xsT[k][base ^ swz];
    acc[0][0] += xv.x * wv.x; acc[0][1] += xv.x * wv.y;
    acc[0][2] += xv.x * wv.z; acc[0][3] += xv.x * wv.w;
    acc[1][0] += xv.y * wv.x; acc[1][1] += xv.y * wv.y;
    acc[1][2] += xv.y * wv.z; acc[1][3] += xv.y * wv.w;
    acc[2][0] += xv.z * wv.x; acc[2][1] += xv.z * wv.y;
    acc[2][2] += xv.z * wv.z; acc[2][3] += xv.z * wv.w;
    acc[3][0] += xv.w * wv.x; acc[3][1] += xv.w * wv.y;
    acc[3][2] += xv.w * wv.z; acc[3][3] += xv.w * wv.w;
  }
#pragma unroll
  for (int e = 0; e < 4; e++) {
    int node = nb + base + e;
    float ps = acc[e][0] * atS[j0] + acc[e][1] * atS[j0 + 1] +
               acc[e][2] * atS[j0 + 2] + acc[e][3] * atS[j0 + 3];
    float pd = acc[e][0] * atD[j0] + acc[e][1] * atD[j0 + 1] +
               acc[e][2] * atD[j0 + 2] + acc[e][3] * atD[j0 + 3];
#pragma unroll
    for (int off = 1; off <= 4; off <<= 1) {
      ps += __shfl_xor(ps, off, 64);
      pd += __shfl_xor(pd, off, 64);
    }
    if (node < NN) {
      uint2 pk;
      pk.x = pack2(acc[e][0], acc[e][1]);
      pk.y = pack2(acc[e][2], acc[e][3]);
      ((uint2*)h2u)[node * 8 + tl] = pk;
      if (tl == 0) { as2[node] = ps * LOG2E; ad2[node] = pd * LOG2E; }
    }
  }
}

// ---------- GAT2 aggregation + bias + BN2 + ReLU, QUAD-node waves ----------
__global__ __launch_bounds__(256, 4) void k_agg2(
    const int* __restrict__ rowp, const int* __restrict__ srcs,
    const uint* __restrict__ h2u, const float* __restrict__ as2,
    const float* __restrict__ ad2, const float* __restrict__ b2v,
    const float* __restrict__ g, const float* __restrict__ bb,
    const float* __restrict__ m, const float* __restrict__ v,
    float* __restrict__ out_emb) {
  int t = threadIdx.x;
  int wid = t >> 6, lane = t & 63;
  int n0 = blockIdx.x * 16 + wid * 4;
  int slot = lane >> 3;
  int fl = lane & 7;                   // feats fl*4..fl*4+3
  int rp[5];
#pragma unroll
  for (int k = 0; k < 5; k++) rp[k] = rowp[n0 + k];
  const uint2* h22 = (const uint2*)h2u;
  float acc[4][4], l[4], adv[4], as[4];
  int p[4], p1[4], lp[4], en[4], s1v[4];
  uint2 w[4];
#pragma unroll
  for (int k = 0; k < 4; k++) {
    adv[k] = ad2[n0 + k];
    en[k] = rp[k + 1];
    lp[k] = en[k] - 1;
    p[k] = rp[k] + slot;
    int pc = p[k] < lp[k] ? p[k] : lp[k];
    int s0 = srcs[pc];                 // pre-scaled s*8 (= uint2 row offset)
    w[k] = h22[s0 + fl];
    as[k] = as2[s0 >> 3];
    p1[k] = p[k] + 8;
    int pc1 = p1[k] < lp[k] ? p1[k] : lp[k];
    s1v[k] = srcs[pc1];
    l[k] = 0.f;
#pragma unroll
    for (int i = 0; i < 4; i++) acc[k][i] = 0.f;
  }
  while (p[0] < en[0] || p[1] < en[1] || p[2] < en[2] || p[3] < en[3]) {
    uint2 wn[4]; float an[4]; int s2[4];
#pragma unroll
    for (int k = 0; k < 4; k++) {
      wn[k] = h22[s1v[k] + fl];
      an[k] = as2[s1v[k] >> 3];
      int p2 = p1[k] + 8;
      int pc = p2 < lp[k] ? p2 : lp[k];
      s2[k] = srcs[pc];
    }
#pragma unroll
    for (int k = 0; k < 4; k++) {
      if (p[k] < en[k]) {
        float e = as[k] + adv[k];
        e = fmaxf(e, 0.2f * e);
        float ex = exp2f(e);
        l[k] += ex;
        acc[k][0] += ex * lo2f(w[k].x); acc[k][1] += ex * hi2r(w[k].x);
        acc[k][2] += ex * lo2f(w[k].y); acc[k][3] += ex * hi2r(w[k].y);
      }
      w[k] = wn[k]; as[k] = an[k]; s1v[k] = s2[k];
      p[k] = p1[k]; p1[k] += 8;
    }
  }
#pragma unroll
  for (int off = 8; off <= 32; off <<= 1) {
#pragma unroll
    for (int k = 0; k < 4; k++) {
#pragma unroll
      for (int i = 0; i < 4; i++) acc[k][i] += __shfl_xor(acc[k][i], off, 64);
      l[k] += __shfl_xor(l[k], off, 64);
    }
  }
  if (slot < 4) {
    float lsum = 0.f, av[4];
#pragma unroll
    for (int i = 0; i < 4; i++) av[i] = 0.f;
#pragma unroll
    for (int k = 0; k < 4; k++) {
      if (slot == k) {
        lsum = l[k];
#pragma unroll
        for (int i = 0; i < 4; i++) av[i] = acc[k][i];
      }
    }
    int node = n0 + slot;
    float li = 1.f / (lsum + 1e-16f);
    int fb = fl * 4;
    float o[4];
#pragma unroll
    for (int i = 0; i < 4; i++) {
      int j = fb + i;
      float ov = av[i] * li + b2v[j];
      ov = (ov - m[j]) * rsqrtf(v[j] + 1e-5f) * g[j] + bb[j];
      o[i] = fmaxf(ov, 0.f);
    }
    *(float4*)(out_emb + node * OUTD + fb) = make_float4(o[0], o[1], o[2], o[3]);
  }
}

// ---------- classifier + regressor heads (thread per node) ----------
__global__ __launch_bounds__(256) void k_mlp(
    const float* __restrict__ embf,
    const float* __restrict__ cw1, const float* __restrict__ cb1,
    const float* __restrict__ cw2, const float* __restrict__ cb2,
    const float* __restrict__ rw1, const float* __restrict__ rb1,
    const float* __restrict__ rw2, const float* __restrict__ rb2,
    float* __restrict__ out_roles, float* __restrict__ out_energy) {
  __shared__ float C1[OUTD * HID2D], R1[OUTD * HID2D];
  __shared__ float C2[HID2D * 3], CB1[HID2D], RB1[HID2D], R2[HID2D];
  __shared__ float CB2v[3], RB2v;
  int t = threadIdx.x;
  for (int i = t; i < OUTD * HID2D; i += 256) { C1[i] = cw1[i]; R1[i] = rw1[i]; }
  if (t < HID2D) { CB1[t] = cb1[t]; RB1[t] = rb1[t]; R2[t] = rw2[t]; }
  if (t < HID2D * 3) C2[t] = cw2[t];
  if (t < 3) CB2v[t] = cb2[t];
  if (t == 0) RB2v = rb2[0];
  __syncthreads();
  int node = blockIdx.x * 256 + t;
  if (node >= NN) return;
  float e[OUTD];
#pragma unroll
  for (int k = 0; k < OUTD; k++) e[k] = embf[node * OUTD + k];
  float r0 = CB2v[0], r1 = CB2v[1], r2 = CB2v[2], en = RB2v;
  for (int j = 0; j < HID2D; j++) {
    float hc = CB1[j], hr = RB1[j];
#pragma unroll
    for (int k = 0; k < OUTD; k++) {
      hc += e[k] * C1[k * HID2D + j];
      hr += e[k] * R1[k * HID2D + j];
    }
    hc = fmaxf(hc, 0.f);
    hr = fmaxf(hr, 0.f);
    r0 += hc * C2[j * 3 + 0];
    r1 += hc * C2[j * 3 + 1];
    r2 += hc * C2[j * 3 + 2];
    en += hr * R2[j];
  }
  out_roles[node * 3 + 0] = r0;
  out_roles[node * 3 + 1] = r1;
  out_roles[node * 3 + 2] = r2;
  out_energy[node] = en;
}

extern "C" void kernel_launch(void* const* d_in, const int* in_sizes, int n_in,
                              void* d_out, int out_size, void* d_ws, size_t ws_size,
                              hipStream_t stream) {
  const float* x    = (const float*)d_in[0];
  const int*   ei   = (const int*)d_in[1];
  const float* W1   = (const float*)d_in[2];
  const float* as1w = (const float*)d_in[3];
  const float* ad1w = (const float*)d_in[4];
  const float* b1   = (const float*)d_in[5];
  const float* W2   = (const float*)d_in[6];
  const float* as2w = (const float*)d_in[7];
  const float* ad2w = (const float*)d_in[8];
  const float* b2v  = (const float*)d_in[9];
  const float* bn1g = (const float*)d_in[10];
  const float* bn1b = (const float*)d_in[11];
  const float* bn1m = (const float*)d_in[12];
  const float* bn1v = (const float*)d_in[13];
  const float* bn2g = (const float*)d_in[14];
  const float* bn2b = (const float*)d_in[15];
  const float* bn2m = (const float*)d_in[16];
  const float* bn2v = (const float*)d_in[17];
  const float* cw1  = (const float*)d_in[18];
  const float* cb1  = (const float*)d_in[19];
  const float* cw2  = (const float*)d_in[20];
  const float* cb2  = (const float*)d_in[21];
  const float* rw1  = (const float*)d_in[22];
  const float* rb1  = (const float*)d_in[23];
  const float* rw2  = (const float*)d_in[24];
  const float* rb2  = (const float*)d_in[25];

  // workspace (~56 MB), no aliasing except h2u reusing dead h1u
  uint*  h1u = (uint*)d_ws;               // N*32 uints (bf16x2) = 12.8MB
  float* hbn = (float*)(h1u + NN * 32);   // N*64 f32 = 25.6MB
  float* as1 = hbn + NN * HIDD;           // N*4
  float* ad1 = as1 + NN * NHEADS;         // N*4
  int* rowp  = (int*)(ad1 + NN * NHEADS); // N+1
  int* srcs  = rowp + NN + 1;             // ETOT
  int* bcur  = srcs + ETOT;               // 512
  int* bins  = bcur + 512;                // NBUCK*CAP = 2.0M ints (8MB)
  uint* h2u  = h1u;                       // N*16 uints fits h1u slot (h1 dead)
  float* as2 = as1;
  float* ad2 = ad1;

  float* out        = (float*)d_out;
  float* out_emb    = out;                   // N*32
  float* out_roles  = out + NN * OUTD;       // N*3
  float* out_energy = out + NN * (OUTD + 3); // N*1

  k_lin1<<<NN / 8, 256, 0, stream>>>(x, W1, as1w, ad1w, h1u, as1, ad1, bcur);
  k_bin<<<(ETOT + EPB - 1) / EPB, 256, 0, stream>>>(ei, bcur, bins);
  k_csr<<<NBUCK, 256, 0, stream>>>(bcur, bins, rowp, srcs);
  k_agg1<<<NN / 16, 256, 0, stream>>>(rowp, srcs, h1u, as1, ad1, b1, bn1g, bn1b, bn1m, bn1v, hbn);
  k_lin2<<<(NN + L2NB - 1) / L2NB, 256, 0, stream>>>(hbn, W2, as2w, ad2w, h2u, as2, ad2);
  k_agg2<<<NN / 16, 256, 0, stream>>>(rowp, srcs, h2u, as2, ad2, b2v, bn2g, bn2b, bn2m, bn2v, out_emb);
  k_mlp<<<(NN + 255) / 256, 256, 0, stream>>>(out_emb, cw1, cb1, cw2, cb2, rw1, rb1, rw2, rb2, out_roles, out_energy);
}

// Round 6
// 291.226 us; speedup vs baseline: 1.3159x; 1.0615x over previous
//
#include <hip/hip_runtime.h>
#include <hip/hip_bf16.h>

#define NN 100000
#define EE 1600000
#define ETOT (EE + NN)          // 1,700,000 edges incl. self-loops
#define IND 32
#define HIDD 64
#define NHEADS 4
#define OUTD 32
#define HID2D 32
#define LOG2E 1.44269504f

#define BSH 8                   // 256 nodes per bucket
#define NBUCK 391               // ceil(NN / 256)
#define CAP 5120                // max edges per bucket (mean ~4348)
#define EPB 8192                // edges per bin block (count + rescatter)
#define L2NB 128                // nodes per k_lin2 block

typedef unsigned int uint;

__device__ __forceinline__ uint pack2(float a, float b) {
  uint lo = (uint)__bfloat16_as_ushort(__float2bfloat16(a));
  uint hi = (uint)__bfloat16_as_ushort(__float2bfloat16(b));
  return (hi << 16) | lo;
}
__device__ __forceinline__ float lo2f(uint w) { return __uint_as_float(w << 16); }
// raw reinterpret: low 16 bits act as <=1-ulp mantissa noise (saves the AND)
__device__ __forceinline__ float hi2r(uint w) { return __uint_as_float(w); }

// ---------- linear 1, LDS-free: h1(bf16) = x @ W1 ; as1/ad1 (pre-scaled) ----------
// Thread per node. Weight rows are block-uniform -> s_load (SMEM pipe, free
// broadcast); x row + 32 accumulators in VGPRs; two sequential j-halves keep
// VGPR ~80 (round-4 spill lesson). Old version: 96 LDS reads/thread -> DS-bound.
// Block 0 also zeroes bcur (replaces a memset dispatch; k_bin runs after).
__global__ __launch_bounds__(256) void k_lin1(
    const float* __restrict__ x, const float* __restrict__ W1,
    const float* __restrict__ atsrc, const float* __restrict__ atdst,
    uint* __restrict__ h1u, float* __restrict__ as1, float* __restrict__ ad1,
    int* __restrict__ bcur) {
  int t = threadIdx.x;
  if (blockIdx.x == 0) { bcur[t] = 0; bcur[t + 256] = 0; }
  int node = blockIdx.x * 256 + t;
  if (node >= NN) return;
  float e[IND];
  const float4* xr = (const float4*)(x + node * IND);
#pragma unroll
  for (int r = 0; r < IND / 4; r++) {
    float4 v = xr[r];
    e[4 * r] = v.x; e[4 * r + 1] = v.y; e[4 * r + 2] = v.z; e[4 * r + 3] = v.w;
  }
  uint* hrow = h1u + node * 32;
#pragma unroll 1
  for (int half = 0; half < 2; half++) {
    float a[32];
#pragma unroll
    for (int j = 0; j < 32; j++) a[j] = 0.f;
#pragma unroll 4
    for (int k = 0; k < IND; k++) {
      const float* wr = W1 + k * HIDD + half * 32;   // uniform -> s_load
      float ek = e[k];
#pragma unroll
      for (int j = 0; j < 32; j++) a[j] += ek * wr[j];
    }
#pragma unroll
    for (int q = 0; q < 16; q++) hrow[half * 16 + q] = pack2(a[2 * q], a[2 * q + 1]);
    // attention dots for the two heads living in this half (head = 16 cols)
#pragma unroll
    for (int hh = 0; hh < 2; hh++) {
      int hd = half * 2 + hh;
      float ps = 0.f, pd = 0.f;
#pragma unroll
      for (int f = 0; f < 16; f++) {
        float av = a[hh * 16 + f];
        ps += av * atsrc[hd * 16 + f];    // uniform -> s_load
        pd += av * atdst[hd * 16 + f];
      }
      as1[node * NHEADS + hd] = ps * LOG2E;
      ad1[node * NHEADS + hd] = pd * LOG2E;
    }
  }
}

// ---------- pass 1: bucket edges by dst>>8 (count, reserve, re-read & scatter) ----------
__global__ __launch_bounds__(256) void k_bin(const int* __restrict__ ei,
                                             int* __restrict__ bcur,
                                             int* __restrict__ bins) {
  __shared__ int cnt[NBUCK];
  int t = threadIdx.x;
  for (int i = t; i < NBUCK; i += 256) cnt[i] = 0;
  __syncthreads();
  int base = blockIdx.x * EPB;
  int lim = base + EPB; if (lim > ETOT) lim = ETOT;
  for (int i = base + t; i < lim; i += 256) {
    int d = (i < EE) ? ei[EE + i] : (i - EE);
    atomicAdd(&cnt[d >> BSH], 1);
  }
  __syncthreads();
  for (int i = t; i < NBUCK; i += 256) cnt[i] = atomicAdd(&bcur[i], cnt[i]);
  __syncthreads();
  for (int i = base + t; i < lim; i += 256) {
    int s, d;
    if (i < EE) { s = ei[i]; d = ei[EE + i]; } else { s = i - EE; d = s; }
    int bk = d >> BSH;
    int pos = atomicAdd(&cnt[bk], 1);
    bins[bk * CAP + pos] = (s << BSH) | (d & ((1 << BSH) - 1));
  }
}

// ---------- pass 2: per-bucket local CSR (391 blocks), inline 512-scan ----------
// srcs entries are stored PRE-SCALED by 8 (uint4/uint2 row offsets).
__global__ __launch_bounds__(256) void k_csr(const int* __restrict__ bcur,
                                             const int* __restrict__ bins,
                                             int* __restrict__ rowp,
                                             int* __restrict__ srcs) {
  __shared__ int lrec[CAP];          // 20KB
  __shared__ int sA[512], sB[512];
  __shared__ int ldeg[256];
  int b = blockIdx.x, t = threadIdx.x;
  if (b == 0 && t == 0) rowp[NN] = ETOT;
  sA[t] = (t < NBUCK) ? bcur[t] : 0;
  sA[t + 256] = (t + 256 < NBUCK) ? bcur[t + 256] : 0;
  __syncthreads();
  int* in = sA; int* out = sB;
  for (int off = 1; off < 512; off <<= 1) {
    for (int i = t; i < 512; i += 256)
      out[i] = in[i] + ((i >= off) ? in[i - off] : 0);
    __syncthreads();
    int* tmp = in; in = out; out = tmp;
  }
  int gb = (b == 0) ? 0 : in[b - 1];
  __syncthreads();
  int count = bcur[b]; if (count > CAP) count = CAP;
  ldeg[t] = 0;
  __syncthreads();
  for (int i = t; i < count; i += 256) {
    int r = bins[b * CAP + i];
    lrec[i] = r;
    atomicAdd(&ldeg[r & 255], 1);
  }
  __syncthreads();
  int dv = ldeg[t];
  sA[t] = dv;
  __syncthreads();
  in = sA; out = sB;
  for (int off = 1; off < 256; off <<= 1) {
    out[t] = in[t] + ((t >= off) ? in[t - off] : 0);
    __syncthreads();
    int* tmp = in; in = out; out = tmp;
  }
  int nb = b << BSH;
  int ex = in[t] - dv;               // exclusive scan
  if (nb + t < NN) rowp[nb + t] = gb + ex;
  ldeg[t] = ex;                      // reuse as scatter cursor
  __syncthreads();
  for (int i = t; i < count; i += 256) {
    int r = lrec[i];
    int pos = atomicAdd(&ldeg[r & 255], 1);
    srcs[gb + pos] = (r >> BSH) << 3;   // pre-scaled src*8
  }
}

// ---------- GAT1 aggregation + bias + BN1 + ReLU, QUAD-node waves ----------
// 4 independent gather pipelines per wave; clamped depth-2 prefetch.
__global__ __launch_bounds__(256, 4) void k_agg1(
    const int* __restrict__ rowp, const int* __restrict__ srcs,
    const uint* __restrict__ h1u, const float* __restrict__ as1,
    const float* __restrict__ ad1, const float* __restrict__ b1,
    const float* __restrict__ g, const float* __restrict__ bb,
    const float* __restrict__ m, const float* __restrict__ v,
    float* __restrict__ hbn) {
  int t = threadIdx.x;
  int wid = t >> 6, lane = t & 63;
  int n0 = blockIdx.x * 16 + wid * 4;
  int slot = lane >> 3;
  int fl = lane & 7;
  int hd = fl >> 1;
  int rp[5];
#pragma unroll
  for (int k = 0; k < 5; k++) rp[k] = rowp[n0 + k];
  const uint4* h14 = (const uint4*)h1u;
  float acc[4][8], l[4], adv[4], as[4];
  int p[4], p1[4], lp[4], en[4], s1v[4];
  uint4 w[4];
#pragma unroll
  for (int k = 0; k < 4; k++) {
    adv[k] = ad1[(n0 + k) * NHEADS + hd];
    en[k] = rp[k + 1];
    lp[k] = en[k] - 1;                 // deg >= 1 (self-loop)
    p[k] = rp[k] + slot;
    int pc = p[k] < lp[k] ? p[k] : lp[k];
    int s0 = srcs[pc];                 // pre-scaled s*8
    w[k] = h14[s0 + fl];
    as[k] = as1[(s0 >> 1) + hd];
    p1[k] = p[k] + 8;
    int pc1 = p1[k] < lp[k] ? p1[k] : lp[k];
    s1v[k] = srcs[pc1];
    l[k] = 0.f;
#pragma unroll
    for (int i = 0; i < 8; i++) acc[k][i] = 0.f;
  }
  while (p[0] < en[0] || p[1] < en[1] || p[2] < en[2] || p[3] < en[3]) {
    uint4 wn[4]; float an[4]; int s2[4];
#pragma unroll
    for (int k = 0; k < 4; k++) {
      wn[k] = h14[s1v[k] + fl];
      an[k] = as1[(s1v[k] >> 1) + hd];
      int p2 = p1[k] + 8;
      int pc = p2 < lp[k] ? p2 : lp[k];
      s2[k] = srcs[pc];
    }
#pragma unroll
    for (int k = 0; k < 4; k++) {
      if (p[k] < en[k]) {
        float e = as[k] + adv[k];
        e = fmaxf(e, 0.2f * e);
        float ex = exp2f(e);           // as/ad pre-scaled by log2e
        l[k] += ex;
        acc[k][0] += ex * lo2f(w[k].x); acc[k][1] += ex * hi2r(w[k].x);
        acc[k][2] += ex * lo2f(w[k].y); acc[k][3] += ex * hi2r(w[k].y);
        acc[k][4] += ex * lo2f(w[k].z); acc[k][5] += ex * hi2r(w[k].z);
        acc[k][6] += ex * lo2f(w[k].w); acc[k][7] += ex * hi2r(w[k].w);
      }
      w[k] = wn[k]; as[k] = an[k]; s1v[k] = s2[k];
      p[k] = p1[k]; p1[k] += 8;
    }
  }
#pragma unroll
  for (int off = 8; off <= 32; off <<= 1) {
#pragma unroll
    for (int k = 0; k < 4; k++) {
#pragma unroll
      for (int i = 0; i < 8; i++) acc[k][i] += __shfl_xor(acc[k][i], off, 64);
      l[k] += __shfl_xor(l[k], off, 64);
    }
  }
  if (slot < 4) {
    float lsum = 0.f, av[8];
#pragma unroll
    for (int i = 0; i < 8; i++) av[i] = 0.f;
#pragma unroll
    for (int k = 0; k < 4; k++) {
      if (slot == k) {
        lsum = l[k];
#pragma unroll
        for (int i = 0; i < 8; i++) av[i] = acc[k][i];
      }
    }
    int node = n0 + slot;
    float li = 1.f / (lsum + 1e-16f);
    int fb = fl * 8;
    float o[8];
#pragma unroll
    for (int i = 0; i < 8; i++) {
      int j = fb + i;
      float ov = av[i] * li + b1[j];
      ov = (ov - m[j]) * rsqrtf(v[j] + 1e-5f) * g[j] + bb[j];
      o[i] = fmaxf(ov, 0.f);
    }
    float4* dst = (float4*)(hbn + node * HIDD + fb);
    dst[0] = make_float4(o[0], o[1], o[2], o[3]);
    dst[1] = make_float4(o[4], o[5], o[6], o[7]);
  }
}

// ---------- linear 2, DS-minimal: h2(bf16) = hbn @ W2 ; as2/ad2 ----------
// 32 nodes per wave (8 j-lane groups x 4 nodes). Per k-step: one b128 W read
// (broadcast across groups, conflict-free) + one b128 read of the transposed,
// XOR-swizzled x tile (8 distinct 16B slots -> all 32 banks) feeds 16 FMA.
// k-loop unroll CAPPED at 4: full unroll -> VGPR 256 -> scratch spill (round 4).
__global__ __launch_bounds__(256) void k_lin2(
    const float* __restrict__ hbn, const float* __restrict__ W2,
    const float* __restrict__ atsrc, const float* __restrict__ atdst,
    uint* __restrict__ h2u, float* __restrict__ as2, float* __restrict__ ad2) {
  __shared__ float xsT[HIDD][L2NB];   // 32KB, transposed + swizzled node slots
  __shared__ float Wp[HIDD * OUTD];   // 8KB, [k][j] as in global
  __shared__ float atS[OUTD], atD[OUTD];
  int t = threadIdx.x;
  int nb = blockIdx.x * L2NB;
  for (int i = t; i < HIDD * OUTD; i += 256) Wp[i] = W2[i];
  if (t < OUTD) { atS[t] = atsrc[t]; atD[t] = atdst[t]; }
#pragma unroll
  for (int i = 0; i < 8; i++) {
    int idx = t + i * 256;
    int node = idx >> 4, c = idx & 15;
    int gnode = nb + node;
    float4 vv = make_float4(0.f, 0.f, 0.f, 0.f);
    if (gnode < NN) vv = ((const float4*)hbn)[gnode * 16 + c];
    int ns = node ^ ((c & 7) << 2);
    xsT[4 * c + 0][ns] = vv.x;
    xsT[4 * c + 1][ns] = vv.y;
    xsT[4 * c + 2][ns] = vv.z;
    xsT[4 * c + 3][ns] = vv.w;
  }
  __syncthreads();
  int w = t >> 6, lane = t & 63;
  int gq = lane >> 3, tl = lane & 7;
  int base = w * 32 + gq * 4;          // logical first node of this lane's quad
  int j0 = tl * 4;                     // 4 output columns per lane
  float acc[4][4];
#pragma unroll
  for (int e = 0; e < 4; e++)
#pragma unroll
    for (int d = 0; d < 4; d++) acc[e][d] = 0.f;
#pragma unroll 4
  for (int k = 0; k < HIDD; k++) {
    float4 wv = *(const float4*)&Wp[k * OUTD + j0];
    int swz = ((k >> 2) & 7) << 2;
    float4 xv = *(const float4*)&xsT[k][base ^ swz];
    acc[0][0] += xv.x * wv.x; acc[0][1] += xv.x * wv.y;
    acc[0][2] += xv.x * wv.z; acc[0][3] += xv.x * wv.w;
    acc[1][0] += xv.y * wv.x; acc[1][1] += xv.y * wv.y;
    acc[1][2] += xv.y * wv.z; acc[1][3] += xv.y * wv.w;
    acc[2][0] += xv.z * wv.x; acc[2][1] += xv.z * wv.y;
    acc[2][2] += xv.z * wv.z; acc[2][3] += xv.z * wv.w;
    acc[3][0] += xv.w * wv.x; acc[3][1] += xv.w * wv.y;
    acc[3][2] += xv.w * wv.z; acc[3][3] += xv.w * wv.w;
  }
#pragma unroll
  for (int e = 0; e < 4; e++) {
    int node = nb + base + e;
    float ps = acc[e][0] * atS[j0] + acc[e][1] * atS[j0 + 1] +
               acc[e][2] * atS[j0 + 2] + acc[e][3] * atS[j0 + 3];
    float pd = acc[e][0] * atD[j0] + acc[e][1] * atD[j0 + 1] +
               acc[e][2] * atD[j0 + 2] + acc[e][3] * atD[j0 + 3];
#pragma unroll
    for (int off = 1; off <= 4; off <<= 1) {
      ps += __shfl_xor(ps, off, 64);
      pd += __shfl_xor(pd, off, 64);
    }
    if (node < NN) {
      uint2 pk;
      pk.x = pack2(acc[e][0], acc[e][1]);
      pk.y = pack2(acc[e][2], acc[e][3]);
      ((uint2*)h2u)[node * 8 + tl] = pk;
      if (tl == 0) { as2[node] = ps * LOG2E; ad2[node] = pd * LOG2E; }
    }
  }
}

// ---------- GAT2 aggregation + bias + BN2 + ReLU, QUAD-node waves ----------
__global__ __launch_bounds__(256, 4) void k_agg2(
    const int* __restrict__ rowp, const int* __restrict__ srcs,
    const uint* __restrict__ h2u, const float* __restrict__ as2,
    const float* __restrict__ ad2, const float* __restrict__ b2v,
    const float* __restrict__ g, const float* __restrict__ bb,
    const float* __restrict__ m, const float* __restrict__ v,
    float* __restrict__ out_emb) {
  int t = threadIdx.x;
  int wid = t >> 6, lane = t & 63;
  int n0 = blockIdx.x * 16 + wid * 4;
  int slot = lane >> 3;
  int fl = lane & 7;                   // feats fl*4..fl*4+3
  int rp[5];
#pragma unroll
  for (int k = 0; k < 5; k++) rp[k] = rowp[n0 + k];
  const uint2* h22 = (const uint2*)h2u;
  float acc[4][4], l[4], adv[4], as[4];
  int p[4], p1[4], lp[4], en[4], s1v[4];
  uint2 w[4];
#pragma unroll
  for (int k = 0; k < 4; k++) {
    adv[k] = ad2[n0 + k];
    en[k] = rp[k + 1];
    lp[k] = en[k] - 1;
    p[k] = rp[k] + slot;
    int pc = p[k] < lp[k] ? p[k] : lp[k];
    int s0 = srcs[pc];                 // pre-scaled s*8 (= uint2 row offset)
    w[k] = h22[s0 + fl];
    as[k] = as2[s0 >> 3];
    p1[k] = p[k] + 8;
    int pc1 = p1[k] < lp[k] ? p1[k] : lp[k];
    s1v[k] = srcs[pc1];
    l[k] = 0.f;
#pragma unroll
    for (int i = 0; i < 4; i++) acc[k][i] = 0.f;
  }
  while (p[0] < en[0] || p[1] < en[1] || p[2] < en[2] || p[3] < en[3]) {
    uint2 wn[4]; float an[4]; int s2[4];
#pragma unroll
    for (int k = 0; k < 4; k++) {
      wn[k] = h22[s1v[k] + fl];
      an[k] = as2[s1v[k] >> 3];
      int p2 = p1[k] + 8;
      int pc = p2 < lp[k] ? p2 : lp[k];
      s2[k] = srcs[pc];
    }
#pragma unroll
    for (int k = 0; k < 4; k++) {
      if (p[k] < en[k]) {
        float e = as[k] + adv[k];
        e = fmaxf(e, 0.2f * e);
        float ex = exp2f(e);
        l[k] += ex;
        acc[k][0] += ex * lo2f(w[k].x); acc[k][1] += ex * hi2r(w[k].x);
        acc[k][2] += ex * lo2f(w[k].y); acc[k][3] += ex * hi2r(w[k].y);
      }
      w[k] = wn[k]; as[k] = an[k]; s1v[k] = s2[k];
      p[k] = p1[k]; p1[k] += 8;
    }
  }
#pragma unroll
  for (int off = 8; off <= 32; off <<= 1) {
#pragma unroll
    for (int k = 0; k < 4; k++) {
#pragma unroll
      for (int i = 0; i < 4; i++) acc[k][i] += __shfl_xor(acc[k][i], off, 64);
      l[k] += __shfl_xor(l[k], off, 64);
    }
  }
  if (slot < 4) {
    float lsum = 0.f, av[4];
#pragma unroll
    for (int i = 0; i < 4; i++) av[i] = 0.f;
#pragma unroll
    for (int k = 0; k < 4; k++) {
      if (slot == k) {
        lsum = l[k];
#pragma unroll
        for (int i = 0; i < 4; i++) av[i] = acc[k][i];
      }
    }
    int node = n0 + slot;
    float li = 1.f / (lsum + 1e-16f);
    int fb = fl * 4;
    float o[4];
#pragma unroll
    for (int i = 0; i < 4; i++) {
      int j = fb + i;
      float ov = av[i] * li + b2v[j];
      ov = (ov - m[j]) * rsqrtf(v[j] + 1e-5f) * g[j] + bb[j];
      o[i] = fmaxf(ov, 0.f);
    }
    *(float4*)(out_emb + node * OUTD + fb) = make_float4(o[0], o[1], o[2], o[3]);
  }
}

// ---------- classifier + regressor heads, LDS-free (thread per node) ----------
// Weight rows are block-uniform -> s_load; emb row + hidden[32] in VGPRs;
// heads sequential to reuse the hidden array (VGPR ~76). Old version issued
// 2048 broadcast ds_read_b32 per thread (stride-128B columns from LDS).
__global__ __launch_bounds__(256) void k_mlp(
    const float* __restrict__ embf,
    const float* __restrict__ cw1, const float* __restrict__ cb1,
    const float* __restrict__ cw2, const float* __restrict__ cb2,
    const float* __restrict__ rw1, const float* __restrict__ rb1,
    const float* __restrict__ rw2, const float* __restrict__ rb2,
    float* __restrict__ out_roles, float* __restrict__ out_energy) {
  int node = blockIdx.x * 256 + threadIdx.x;
  if (node >= NN) return;
  float e[OUTD];
  const float4* er = (const float4*)(embf + node * OUTD);
#pragma unroll
  for (int r = 0; r < OUTD / 4; r++) {
    float4 v = er[r];
    e[4 * r] = v.x; e[4 * r + 1] = v.y; e[4 * r + 2] = v.z; e[4 * r + 3] = v.w;
  }
  float h[HID2D];
  // classifier head
#pragma unroll
  for (int j = 0; j < HID2D; j++) h[j] = cb1[j];
#pragma unroll 4
  for (int k = 0; k < OUTD; k++) {
    const float* wr = cw1 + k * HID2D;   // uniform -> s_load
    float ek = e[k];
#pragma unroll
    for (int j = 0; j < HID2D; j++) h[j] += ek * wr[j];
  }
  float r0 = cb2[0], r1 = cb2[1], r2 = cb2[2];
#pragma unroll
  for (int j = 0; j < HID2D; j++) {
    float hv = fmaxf(h[j], 0.f);
    r0 += hv * cw2[j * 3 + 0];
    r1 += hv * cw2[j * 3 + 1];
    r2 += hv * cw2[j * 3 + 2];
  }
  out_roles[node * 3 + 0] = r0;
  out_roles[node * 3 + 1] = r1;
  out_roles[node * 3 + 2] = r2;
  // regressor head (reuses h)
#pragma unroll
  for (int j = 0; j < HID2D; j++) h[j] = rb1[j];
#pragma unroll 4
  for (int k = 0; k < OUTD; k++) {
    const float* wr = rw1 + k * HID2D;   // uniform -> s_load
    float ek = e[k];
#pragma unroll
    for (int j = 0; j < HID2D; j++) h[j] += ek * wr[j];
  }
  float en = rb2[0];
#pragma unroll
  for (int j = 0; j < HID2D; j++) en += fmaxf(h[j], 0.f) * rw2[j];
  out_energy[node] = en;
}

extern "C" void kernel_launch(void* const* d_in, const int* in_sizes, int n_in,
                              void* d_out, int out_size, void* d_ws, size_t ws_size,
                              hipStream_t stream) {
  const float* x    = (const float*)d_in[0];
  const int*   ei   = (const int*)d_in[1];
  const float* W1   = (const float*)d_in[2];
  const float* as1w = (const float*)d_in[3];
  const float* ad1w = (const float*)d_in[4];
  const float* b1   = (const float*)d_in[5];
  const float* W2   = (const float*)d_in[6];
  const float* as2w = (const float*)d_in[7];
  const float* ad2w = (const float*)d_in[8];
  const float* b2v  = (const float*)d_in[9];
  const float* bn1g = (const float*)d_in[10];
  const float* bn1b = (const float*)d_in[11];
  const float* bn1m = (const float*)d_in[12];
  const float* bn1v = (const float*)d_in[13];
  const float* bn2g = (const float*)d_in[14];
  const float* bn2b = (const float*)d_in[15];
  const float* bn2m = (const float*)d_in[16];
  const float* bn2v = (const float*)d_in[17];
  const float* cw1  = (const float*)d_in[18];
  const float* cb1  = (const float*)d_in[19];
  const float* cw2  = (const float*)d_in[20];
  const float* cb2  = (const float*)d_in[21];
  const float* rw1  = (const float*)d_in[22];
  const float* rb1  = (const float*)d_in[23];
  const float* rw2  = (const float*)d_in[24];
  const float* rb2  = (const float*)d_in[25];

  // workspace (~56 MB), no aliasing except h2u reusing dead h1u
  uint*  h1u = (uint*)d_ws;               // N*32 uints (bf16x2) = 12.8MB
  float* hbn = (float*)(h1u + NN * 32);   // N*64 f32 = 25.6MB
  float* as1 = hbn + NN * HIDD;           // N*4
  float* ad1 = as1 + NN * NHEADS;         // N*4
  int* rowp  = (int*)(ad1 + NN * NHEADS); // N+1
  int* srcs  = rowp + NN + 1;             // ETOT
  int* bcur  = srcs + ETOT;               // 512
  int* bins  = bcur + 512;                // NBUCK*CAP = 2.0M ints (8MB)
  uint* h2u  = h1u;                       // N*16 uints fits h1u slot (h1 dead)
  float* as2 = as1;
  float* ad2 = ad1;

  float* out        = (float*)d_out;
  float* out_emb    = out;                   // N*32
  float* out_roles  = out + NN * OUTD;       // N*3
  float* out_energy = out + NN * (OUTD + 3); // N*1

  k_lin1<<<NBUCK, 256, 0, stream>>>(x, W1, as1w, ad1w, h1u, as1, ad1, bcur);
  k_bin<<<(ETOT + EPB - 1) / EPB, 256, 0, stream>>>(ei, bcur, bins);
  k_csr<<<NBUCK, 256, 0, stream>>>(bcur, bins, rowp, srcs);
  k_agg1<<<NN / 16, 256, 0, stream>>>(rowp, srcs, h1u, as1, ad1, b1, bn1g, bn1b, bn1m, bn1v, hbn);
  k_lin2<<<(NN + L2NB - 1) / L2NB, 256, 0, stream>>>(hbn, W2, as2w, ad2w, h2u, as2, ad2);
  k_agg2<<<NN / 16, 256, 0, stream>>>(rowp, srcs, h2u, as2, ad2, b2v, bn2g, bn2b, bn2m, bn2v, out_emb);
  k_mlp<<<(NN + 255) / 256, 256, 0, stream>>>(out_emb, cw1, cb1, cw2, cb2, rw1, rb1, rw2, rb2, out_roles, out_energy);
}